// Round 2
// baseline (302.392 us; speedup 1.0000x reference)
//
#include <hip/hip_runtime.h>

// ---------------------------------------------------------------------------
// B=8, S=4096 (rows=32768), D=1024, DS=64
// segments: qk 512 (tiles 0-31) | v 256 (32-47) | rel 128 (48-55) | val 64 (56-59)
// R5: true-depth pipelines. Proj: x staged via global_load_lds into a 5-slot
// ring (depth-4 in flight), W-frags loaded in 4-kstep groups (reg dbuf) so the
// counted vmcnt(11) is never tightened by interleaved loads; ONE barrier/kstep.
// Agg: e-frags depth-2 via 3-buffer rotation (15 = 3x5, static roles).
// ---------------------------------------------------------------------------

typedef short short8 __attribute__((ext_vector_type(8)));   // 8 bf16 = 4 VGPR
typedef float f32x4 __attribute__((ext_vector_type(4)));
typedef unsigned int uint4v __attribute__((ext_vector_type(4)));

__device__ __forceinline__ unsigned short f32_to_bf16(float f) {
  unsigned u = __float_as_uint(f);
  u += 0x7FFF + ((u >> 16) & 1);  // RNE
  return (unsigned short)(u >> 16);
}
__device__ __forceinline__ float bf16_to_f32(unsigned short h) {
  return __uint_as_float(((unsigned)h) << 16);
}

// packed f32->bf16 RNE, 2 at a time (hw instruction; low half = first operand)
__device__ __forceinline__ unsigned cvt_pk_bf16(float a, float b) {
  unsigned r;
  asm("v_cvt_pk_bf16_f32 %0, %1, %2" : "=v"(r) : "v"(a), "v"(b));
  return r;
}

// split 8 f32 -> hi/lo bf16 frags (hi = RNE(v), lo = RNE(v - hi))
__device__ __forceinline__ void split8v(const f32x4& v0, const f32x4& v1,
                                        short8& hi, short8& lo) {
  unsigned hp[4], lp[4];
#pragma unroll
  for (int j = 0; j < 4; ++j) {
    float a = (j < 2) ? v0[2 * j] : v1[2 * j - 4];
    float b = (j < 2) ? v0[2 * j + 1] : v1[2 * j - 3];
    unsigned p = cvt_pk_bf16(a, b);
    float ra = a - __uint_as_float(p << 16);
    float rb = b - __uint_as_float(p & 0xFFFF0000u);
    hp[j] = p;
    lp[j] = cvt_pk_bf16(ra, rb);
  }
  hi = __builtin_bit_cast(short8, (uint4v){hp[0], hp[1], hp[2], hp[3]});
  lo = __builtin_bit_cast(short8, (uint4v){lp[0], lp[1], lp[2], lp[3]});
}

#define MFMA(a, b, c) __builtin_amdgcn_mfma_f32_16x16x32_bf16(a, b, c, 0, 0, 0)

typedef const __attribute__((address_space(1))) unsigned int guint;
typedef __attribute__((address_space(3))) unsigned int luint;
// async global->LDS, 16 B per lane; LDS dest = wave-uniform base + lane*16
__device__ __forceinline__ void stage16(const float* g, float* l) {
  __builtin_amdgcn_global_load_lds((guint*)g, (luint*)l, 16, 0, 0);
}
__device__ __forceinline__ void bar() {
  asm volatile("" ::: "memory");
  __builtin_amdgcn_s_barrier();
  asm volatile("" ::: "memory");
}

// ---- k_prep: zero wg; split proj_w -> whi/wlo; normalize+split emb -> ehi/elo ----
__global__ __launch_bounds__(256) void k_prep(const float* __restrict__ pw,
                                              const float* __restrict__ emb,
                                              unsigned short* __restrict__ whi,
                                              unsigned short* __restrict__ wlo,
                                              unsigned short* __restrict__ ehi,
                                              unsigned short* __restrict__ elo,
                                              float* __restrict__ wg) {
  int tid = blockIdx.x * 256 + threadIdx.x;
  if (tid < 7680) wg[tid] = 0.f;
  for (int i = tid; i < 65536; i += gridDim.x * 256) {
    float v = pw[i];
    unsigned short h = f32_to_bf16(v);
    whi[i] = h;
    wlo[i] = f32_to_bf16(v - bf16_to_f32(h));
  }
  int wid = tid >> 6, lane = tid & 63;
  int nw = gridDim.x * 4;
  for (int n = wid; n < 960; n += nw) {
    float v = emb[n * 64 + lane];
    float s = v * v;
#pragma unroll
    for (int off = 1; off < 64; off <<= 1) s += __shfl_xor(s, off);
    float vn = v / sqrtf(s);
    unsigned short h = f32_to_bf16(vn);
    ehi[n * 64 + lane] = h;
    elo[n * 64 + lane] = f32_to_bf16(vn - bf16_to_f32(h));
  }
}

// ---- k_main: fused proj (x@W^T+b) + agg (softmax-weighted emb logits) ----
__global__ __launch_bounds__(256, 4) void k_main(
    const float* __restrict__ x, const unsigned short* __restrict__ whi,
    const unsigned short* __restrict__ wlo, const float* __restrict__ pb,
    const unsigned short* __restrict__ ehi, const unsigned short* __restrict__ elo,
    const float* __restrict__ imp, float* __restrict__ wg) {
  __shared__ __align__(16) float xt[5][32][32];           // 20 KiB ring (5 slots)
  __shared__ __align__(16) unsigned short hxh[32][64];    // 4 KiB h hi
  __shared__ __align__(16) unsigned short hxl[32][64];    // 4 KiB h lo
  __shared__ float zpart[4][32][4];
  __shared__ float coefL[32][4];

  const int tid = threadIdx.x, w = tid >> 6, lane = tid & 63;
  const int q = lane >> 4, c = lane & 15;
  const int row0 = blockIdx.x * 32;
  const int nt0 = w;

  // staging: thread t fills LDS bytes [t*16,t*16+16) = row t>>3, phys slot t&7.
  // desired layout: phys_colbyte = logical_colbyte ^ ((row&7)<<4)  -> source
  // col is pre-swizzled so LDS dest stays linear (global_load_lds requirement).
  const int srow = tid >> 3;
  const int scol = ((tid & 7) ^ (srow & 7)) * 4;
  const float* sbase = x + (size_t)(row0 + srow) * 1024 + scol;
  auto STAGEX = [&](int slot, int ks) {
    stage16(sbase + ks * 32, &xt[slot][0][0] + (w << 8));  // wave base: w*1KiB
  };

  // proj B (W^T) fragment base pointers
  const unsigned short* bwh = whi + (size_t)(nt0 * 16 + c) * 1024 + q * 8;
  const unsigned short* bwl = wlo + (size_t)(nt0 * 16 + c) * 1024 + q * 8;

  f32x4 acc0 = {0.f, 0.f, 0.f, 0.f}, acc1 = {0.f, 0.f, 0.f, 0.f};

  // swizzled read offsets (hoisted; per-thread constant)
  const unsigned sw = (unsigned)((c & 7) << 4);
  const unsigned off1 = ((unsigned)(q * 32)) ^ sw;
  const unsigned off2 = ((unsigned)(q * 32 + 16)) ^ sw;
  const char* xby = (const char*)&xt[0][0][0] + (size_t)c * 128;

  auto projstep = [&](int slot, short8 B_hi, short8 B_lo) {
    const char* bp = xby + slot * 4096;
    f32x4 a0 = *(const f32x4*)(bp + off1);          // rows c      (mt=0)
    f32x4 a1 = *(const f32x4*)(bp + off2);
    f32x4 a2 = *(const f32x4*)(bp + 2048 + off1);   // rows 16+c   (mt=1)
    f32x4 a3 = *(const f32x4*)(bp + 2048 + off2);
    short8 ah, al;
    split8v(a0, a1, ah, al);
    acc0 = MFMA(ah, B_hi, acc0);
    acc0 = MFMA(ah, B_lo, acc0);
    acc0 = MFMA(al, B_hi, acc0);
    split8v(a2, a3, ah, al);
    acc1 = MFMA(ah, B_hi, acc1);
    acc1 = MFMA(ah, B_lo, acc1);
    acc1 = MFMA(al, B_hi, acc1);
  };

  // ---------------- proj K-loop: 32 ksteps, depth-4 staging ----------------
  short8 BhA[4], BlA[4], BhB[4], BlB[4];
#pragma unroll
  for (int kk = 0; kk < 4; ++kk) {
    BhA[kk] = *(const short8*)(bwh + kk * 32);
    BlA[kk] = *(const short8*)(bwl + kk * 32);
  }
  STAGEX(0, 0); STAGEX(1, 1); STAGEX(2, 2); STAGEX(3, 3);
  int rs = 0, wsl = 4;  // read slot = ks%5, write slot = (ks+4)%5

  // Per group g (ksteps 4g..4g+3): issue batch(g+1) (8 loads), then 4 iters of
  // {vmcnt(11); barrier; STAGE(ks+4); compute}.  Newer-than-STAGE(ks) at the
  // wait = 3 stages + 8 batch loads = 11 exactly (verified for all g,p incl.
  // prologue).  STAGE(ks+4) writes slot (ks-1)%5, whose reads completed before
  // this iteration's barrier -> single barrier is safe.
  auto group = [&](int g, short8 (&ch)[4], short8 (&cl)[4],
                   short8 (&nh)[4], short8 (&nl)[4]) {
#pragma unroll
    for (int kk = 0; kk < 4; ++kk) {
      nh[kk] = *(const short8*)(bwh + ((g + 1) * 4 + kk) * 32);
      nl[kk] = *(const short8*)(bwl + ((g + 1) * 4 + kk) * 32);
    }
#pragma unroll
    for (int p = 0; p < 4; ++p) {
      asm volatile("s_waitcnt vmcnt(11)" ::: "memory");
      bar();
      STAGEX(wsl, 4 * g + p + 4);
      projstep(rs, ch[p], cl[p]);
      ++rs; if (rs == 5) rs = 0;
      ++wsl; if (wsl == 5) wsl = 0;
    }
  };
  group(0, BhA, BlA, BhB, BlB);
  group(1, BhB, BlB, BhA, BlA);
  group(2, BhA, BlA, BhB, BlB);
  group(3, BhB, BlB, BhA, BlA);
  group(4, BhA, BlA, BhB, BlB);
  group(5, BhB, BlB, BhA, BlA);
  group(6, BhA, BlA, BhB, BlB);
  // epilogue group 7 (ks 28..31): B in BhB/BlB, no new stages; exact counts.
  asm volatile("s_waitcnt vmcnt(3)" ::: "memory"); bar();
  projstep(rs, BhB[0], BlB[0]); ++rs; if (rs == 5) rs = 0;
  asm volatile("s_waitcnt vmcnt(2)" ::: "memory"); bar();
  projstep(rs, BhB[1], BlB[1]); ++rs; if (rs == 5) rs = 0;
  asm volatile("s_waitcnt vmcnt(1)" ::: "memory"); bar();
  projstep(rs, BhB[2], BlB[2]); ++rs; if (rs == 5) rs = 0;
  asm volatile("s_waitcnt vmcnt(0)" ::: "memory"); bar();
  projstep(rs, BhB[3], BlB[3]);

  // ---------------- h epilogue -> swizzled LDS exchange ----------------
  float bias = pb[nt0 * 16 + c];
#pragma unroll
  for (int mt = 0; mt < 2; ++mt) {
    f32x4 a = mt ? acc1 : acc0;
#pragma unroll
    for (int r = 0; r < 4; ++r) {
      float val = a[r] + bias;  // C: row=(q*4+r), col=c
      int row = mt * 16 + q * 4 + r;
      unsigned colb = (unsigned)((nt0 * 16 + c) * 2);
      unsigned o = (unsigned)(row * 128) + (colb ^ ((unsigned)(row & 7) << 4));
      unsigned short h = f32_to_bf16(val);
      *(unsigned short*)((char*)&hxh[0][0] + o) = h;
      *(unsigned short*)((char*)&hxl[0][0] + o) = f32_to_bf16(val - bf16_to_f32(h));
    }
  }
  __syncthreads();

  // agg A-frags (persist in VGPRs for both passes)
  short8 Ahi[2][2], Alo[2][2];
#pragma unroll
  for (int mt = 0; mt < 2; ++mt) {
    int row = mt * 16 + c;
    unsigned rsw = (unsigned)((row & 7) << 4);
#pragma unroll
    for (int k2 = 0; k2 < 2; ++k2) {
      unsigned o = (unsigned)(row * 128) + (((unsigned)(k2 * 64 + q * 16)) ^ rsw);
      Ahi[mt][k2] = *(const short8*)((const char*)&hxh[0][0] + o);
      Alo[mt][k2] = *(const short8*)((const char*)&hxl[0][0] + o);
    }
  }

  const size_t ebq = (size_t)c * 64 + q * 8;
  short8 eA[4], eB[4], eC[4];
  auto LOADE = [&](short8 (&d)[4], int i) {
    size_t eb = (size_t)(w + 4 * i) * 1024 + ebq;
    d[0] = *(const short8*)(ehi + eb);
    d[1] = *(const short8*)(ehi + eb + 32);
    d[2] = *(const short8*)(elo + eb);
    d[3] = *(const short8*)(elo + eb + 32);
  };

  // ---------------- pass 1: segment Z (depth-2 e-prefetch, 3-buf) ----------
  f32x4 zacc0 = {0.f, 0.f, 0.f, 0.f}, zacc1 = {0.f, 0.f, 0.f, 0.f};
  auto zflush = [&](int seg) {
#pragma unroll
    for (int mt = 0; mt < 2; ++mt)
#pragma unroll
      for (int r = 0; r < 4; ++r) {
        float v = mt ? zacc1[r] : zacc0[r];
        v += __shfl_xor(v, 1); v += __shfl_xor(v, 2);
        v += __shfl_xor(v, 4); v += __shfl_xor(v, 8);
        if (c == 0) zpart[w][mt * 16 + q * 4 + r][seg] = v;
      }
    zacc0 = (f32x4){0.f, 0.f, 0.f, 0.f};
    zacc1 = (f32x4){0.f, 0.f, 0.f, 0.f};
  };

  int cur_seg = 0;
  auto step1 = [&](int i, short8 (&e)[4]) {
    int nt = w + 4 * i;
    int s = (nt < 32) ? 0 : (nt < 48) ? 1 : (nt < 56) ? 2 : 3;
    if (s != cur_seg) { zflush(cur_seg); cur_seg = s; }
#pragma unroll
    for (int mt = 0; mt < 2; ++mt) {
      f32x4 l = {0.f, 0.f, 0.f, 0.f};
      l = MFMA(Ahi[mt][0], e[0], l); l = MFMA(Ahi[mt][1], e[1], l);
      l = MFMA(Ahi[mt][0], e[2], l); l = MFMA(Ahi[mt][1], e[3], l);
      l = MFMA(Alo[mt][0], e[0], l); l = MFMA(Alo[mt][1], e[1], l);
#pragma unroll
      for (int r = 0; r < 4; ++r) {
        if (mt == 0) zacc0[r] += __expf(l[r]); else zacc1[r] += __expf(l[r]);
      }
    }
  };
  LOADE(eA, 0); LOADE(eB, 1);
  for (int j = 0; j < 5; ++j) {
    LOADE(eC, 3 * j + 2);            step1(3 * j, eA);
    if (j < 4) LOADE(eA, 3 * j + 3); step1(3 * j + 1, eB);
    if (j < 4) LOADE(eB, 3 * j + 4); step1(3 * j + 2, eC);
  }
  zflush(cur_seg);
  __syncthreads();
  if (tid < 128) {  // combine: 128 threads = 32 rows x 4 segs
    int row = tid & 31, sg = tid >> 5;
    float Z = zpart[0][row][sg] + zpart[1][row][sg] + zpart[2][row][sg] + zpart[3][row][sg];
    coefL[row][sg] = imp[row0 + row] / Z;
  }
  __syncthreads();

  // ---------------- pass 2: weighted exp accumulation ----------------
  const int bIdx = row0 >> 12;
  f32x4 cf0, cf1;
  int cs2 = -1;
  auto step2 = [&](int i, short8 (&e)[4]) {
    int nt = w + 4 * i;
    int s = (nt < 32) ? 0 : (nt < 48) ? 1 : (nt < 56) ? 2 : 3;
    if (s != cs2) {
#pragma unroll
      for (int r = 0; r < 4; ++r) {
        cf0[r] = coefL[q * 4 + r][s];
        cf1[r] = coefL[16 + q * 4 + r][s];
      }
      cs2 = s;
    }
    float wsum = 0.f;
#pragma unroll
    for (int mt = 0; mt < 2; ++mt) {
      f32x4 l = {0.f, 0.f, 0.f, 0.f};
      l = MFMA(Ahi[mt][0], e[0], l); l = MFMA(Ahi[mt][1], e[1], l);
      l = MFMA(Ahi[mt][0], e[2], l); l = MFMA(Ahi[mt][1], e[3], l);
      l = MFMA(Alo[mt][0], e[0], l); l = MFMA(Alo[mt][1], e[1], l);
#pragma unroll
      for (int r = 0; r < 4; ++r)
        wsum = fmaf(__expf(l[r]), mt ? cf1[r] : cf0[r], wsum);
    }
    wsum += __shfl_xor(wsum, 16);
    wsum += __shfl_xor(wsum, 32);  // lanes sharing col c now hold all 32 rows' sum
    if (lane < 16) atomicAdd(&wg[bIdx * 960 + nt * 16 + c], wsum);
  };
  LOADE(eA, 0); LOADE(eB, 1);
  for (int j = 0; j < 5; ++j) {
    LOADE(eC, 3 * j + 2);            step2(3 * j, eA);
    if (j < 4) LOADE(eA, 3 * j + 3); step2(3 * j + 1, eB);
    if (j < 4) LOADE(eB, 3 * j + 4); step2(3 * j + 2, eC);
  }
}

// ---- k_topk: parallel rank-based selection + ballot emission ----
__global__ __launch_bounds__(256) void k_topk(const float* __restrict__ wg,
                                              float* __restrict__ out) {
  __shared__ float vals[512];
  __shared__ int flags[512];
  int blk = blockIdx.x;
  int b = blk >> 2, t = blk & 3;
  int tid = threadIdx.x;
  const int Ns[4] = {512, 256, 128, 64};
  const int Ks[4] = {64, 32, 16, 3};
  const int Off[4] = {0, 512, 768, 896};
  int N = Ns[t], K = Ks[t], off = Off[t];
  for (int n = tid; n < N; n += 256) vals[n] = wg[b * 960 + off + n];
  __syncthreads();
  for (int n = tid; n < N; n += 256) {
    float v = vals[n];
    int rank = 0;
    for (int m = 0; m < N; ++m) {  // LDS broadcast reads, fully parallel
      float u = vals[m];
      rank += (u > v || (u == v && m < n)) ? 1 : 0;
    }
    flags[n] = (rank < K) ? 1 : 0;
  }
  __syncthreads();
  if (t <= 1) {  // index outputs: sorted ascending via ballot prefix (wave 0)
    if (tid < 64) {
      int base = 0;
      for (int ch = 0; ch < N; ch += 64) {
        int n = ch + tid;
        int f = flags[n];
        unsigned long long mask = __ballot(f);
        if (f) {
          int pos = base + __popcll(mask & ((1ull << tid) - 1ull));
          if (t == 0) out[b * 64 + pos] = (float)n;
          else out[512 + b * 32 + pos] = (float)n;
        }
        base += __popcll(mask);
      }
    }
  } else if (t == 2) {  // rel_Q and rel_K (identical sparse vectors)
    for (int n = tid; n < 128; n += 256) {
      float v = flags[n] ? vals[n] : 0.f;
      out[768 + b * 128 + n] = v;
      out[1792 + b * 128 + n] = v;
    }
  } else {  // val_w
    for (int n = tid; n < 64; n += 256) {
      float v = flags[n] ? vals[n] : 0.f;
      out[2816 + b * 64 + n] = v;
    }
  }
}

extern "C" void kernel_launch(void* const* d_in, const int* in_sizes, int n_in,
                              void* d_out, int out_size, void* d_ws, size_t ws_size,
                              hipStream_t stream) {
  const float* x   = (const float*)d_in[0];   // 8*4096*1024
  const float* imp = (const float*)d_in[1];   // 8*4096
  const float* pw  = (const float*)d_in[2];   // 64*1024
  const float* pb  = (const float*)d_in[3];   // 64
  const float* emb = (const float*)d_in[4];   // 1216*64
  float* out = (float*)d_out;                 // 3328 floats

  char* ws = (char*)d_ws;
  unsigned short* whi = (unsigned short*)(ws);             // 128 KiB
  unsigned short* wlo = (unsigned short*)(ws + 131072);    // 128 KiB
  unsigned short* ehi = (unsigned short*)(ws + 262144);    // 120 KiB
  unsigned short* elo = (unsigned short*)(ws + 385024);    // 120 KiB
  float*          wg  = (float*)(ws + 507904);             // 30 KiB

  hipLaunchKernelGGL(k_prep, dim3(64), dim3(256), 0, stream, pw, emb, whi, wlo, ehi, elo, wg);
  hipLaunchKernelGGL(k_main, dim3(1024), dim3(256), 0, stream, x, whi, wlo, pb, ehi, elo, imp, wg);
  hipLaunchKernelGGL(k_topk, dim3(32), dim3(256), 0, stream, wg, out);
}